// Round 1
// baseline (1180.823 us; speedup 1.0000x reference)
//
#include <hip/hip_runtime.h>
#include <stdint.h>

typedef __attribute__((ext_vector_type(8))) short   bfrag_t;  // 8 bf16 = 4 VGPRs (MFMA A/B frag)
typedef __attribute__((ext_vector_type(4))) float   facc_t;   // 4 f32 (MFMA C/D frag)
typedef __attribute__((ext_vector_type(4))) float   f4_t;
typedef __attribute__((ext_vector_type(8))) ushort  u16x8_t;

__device__ __forceinline__ ushort f2bf(float f) {
  union { float f; uint32_t u; } c; c.f = f;
  uint32_t u = c.u;
  return (ushort)((u + 0x7FFFu + ((u >> 16) & 1u)) >> 16);  // RNE
}

__device__ __forceinline__ void gload_lds16(const void* g, void* l) {
  auto gp = reinterpret_cast<__attribute__((address_space(1))) void*>(
      reinterpret_cast<uintptr_t>(g));
  auto lp = reinterpret_cast<__attribute__((address_space(3))) void*>(
      reinterpret_cast<uintptr_t>(l));
  __builtin_amdgcn_global_load_lds(gp, lp, 16, 0, 0);
}

// ---------------- fused x = input+bias+residual ; h = LN(x)*ln_w + attn_nb ----------------
__global__ __launch_bounds__(256) void add_ln_kernel(
    const float* __restrict__ in, const float* __restrict__ res,
    const float* __restrict__ bias, const float* __restrict__ lnw,
    const float* __restrict__ lnb, float* __restrict__ x, ushort* __restrict__ h)
{
  const int row = blockIdx.x;
  const int t = threadIdx.x;
  const size_t base = (size_t)row * 2048;

  f4_t v0 = ((const f4_t*)(in  + base))[t*2];
  f4_t v1 = ((const f4_t*)(in  + base))[t*2+1];
  f4_t r0 = ((const f4_t*)(res + base))[t*2];
  f4_t r1 = ((const f4_t*)(res + base))[t*2+1];
  f4_t b0 = ((const f4_t*)bias)[t*2];
  f4_t b1 = ((const f4_t*)bias)[t*2+1];

  float xv[8];
  float s = 0.f, ss = 0.f;
  #pragma unroll
  for (int j = 0; j < 4; ++j) {
    float a = v0[j] + b0[j] + r0[j];
    float b = v1[j] + b1[j] + r1[j];
    xv[j] = a; xv[4+j] = b;
    s += a + b; ss += a*a + b*b;
  }
  ((f4_t*)(x + base))[t*2]   = *(f4_t*)&xv[0];
  ((f4_t*)(x + base))[t*2+1] = *(f4_t*)&xv[4];

  #pragma unroll
  for (int off = 32; off > 0; off >>= 1) {
    s  += __shfl_down(s, off, 64);
    ss += __shfl_down(ss, off, 64);
  }
  __shared__ float red[8];
  __shared__ float mrs[2];
  if ((t & 63) == 0) { red[t>>6] = s; red[4 + (t>>6)] = ss; }
  __syncthreads();
  if (t == 0) {
    float S  = red[0]+red[1]+red[2]+red[3];
    float SS = red[4]+red[5]+red[6]+red[7];
    float mu  = S * (1.f/2048.f);
    float var = SS * (1.f/2048.f) - mu*mu;
    mrs[0] = mu; mrs[1] = rsqrtf(var + 1e-5f);
  }
  __syncthreads();
  const float mu = mrs[0], rs = mrs[1];

  f4_t w0 = ((const f4_t*)lnw)[t*2], w1 = ((const f4_t*)lnw)[t*2+1];
  f4_t n0 = ((const f4_t*)lnb)[t*2], n1 = ((const f4_t*)lnb)[t*2+1];
  u16x8_t hv;
  #pragma unroll
  for (int j = 0; j < 4; ++j) {
    hv[j]   = f2bf((xv[j]   - mu) * rs * w0[j] + n0[j]);
    hv[4+j] = f2bf((xv[4+j] - mu) * rs * w1[j] + n1[j]);
  }
  *(u16x8_t*)(h + base + t*8) = hv;
}

// ---------------- transpose + fp32->bf16 cast: W[K][N] -> Bt[N][K] ----------------
__global__ __launch_bounds__(256) void tcast_kernel(
    const float* __restrict__ W, ushort* __restrict__ Bt, int K, int N)
{
  __shared__ float lds[64][65];
  const int tx = threadIdx.x, ty = threadIdx.y;
  const int n0 = blockIdx.x * 64, k0 = blockIdx.y * 64;
  #pragma unroll
  for (int rr = 0; rr < 16; ++rr) {
    int row = rr * 4 + ty;
    lds[row][tx] = W[(size_t)(k0 + row) * N + n0 + tx];
  }
  __syncthreads();
  const int t  = tx + ty * 64;
  const int kc = (t & 7) * 8;
  #pragma unroll
  for (int it = 0; it < 2; ++it) {
    int nr = (t >> 3) + it * 32;
    u16x8_t o;
    #pragma unroll
    for (int j = 0; j < 8; ++j) o[j] = f2bf(lds[kc + j][nr]);
    *(u16x8_t*)(&Bt[(size_t)(n0 + nr) * K + k0 + kc]) = o;
  }
}

// ---------------- bf16 GEMM, A[M][K] x Bt[N][K]^T, m97 structure ----------------
// EPI==0: out = bf16(relu(acc + bias[n]))       (h1)
// EPI==1: out = f32(acc + bias[n] + addend[m][n]) (final)
template<int EPI>
__global__ __launch_bounds__(256) void gemm_bt_kernel(
    const ushort* __restrict__ A, const ushort* __restrict__ Bt,
    const float* __restrict__ bias, const float* __restrict__ addend,
    void* __restrict__ outp, int M, int N, int K)
{
  __shared__ ushort As[128*64];
  __shared__ ushort Bs[128*64];
  const int tid  = threadIdx.x;
  const int lane = tid & 63, w = tid >> 6;
  const int nwg  = gridDim.x;
  const int bid  = blockIdx.x;
  const int swz  = (bid & 7) * (nwg >> 3) + (bid >> 3);   // nwg % 8 == 0 here -> bijective
  const int nbn  = N >> 7;
  const int bm   = swz / nbn, bn = swz % nbn;
  const size_t aBase = (size_t)bm * 128 * K;
  const size_t bBase = (size_t)bn * 128 * K;
  const int fr = lane & 15, kg = lane >> 4;
  const int wr = (w >> 1) * 64, wc = (w & 1) * 64;

  facc_t acc[4][4] = {};

  for (int k0 = 0; k0 < K; k0 += 64) {
    #pragma unroll
    for (int j = 0; j < 4; ++j) {
      const int eo = w * 2048 + j * 512 + lane * 8;   // bf16 elems within 128x64 tile
      const int rr = eo >> 6, cc = eo & 63;
      gload_lds16(&A [aBase + (size_t)rr * K + k0 + cc], &As[w*2048 + j*512]);
      gload_lds16(&Bt[bBase + (size_t)rr * K + k0 + cc], &Bs[w*2048 + j*512]);
    }
    __syncthreads();
    #pragma unroll
    for (int kk = 0; kk < 64; kk += 32) {
      bfrag_t af[4], bfr[4];
      #pragma unroll
      for (int m = 0; m < 4; ++m)
        af[m] = *(const bfrag_t*)&As[(wr + m*16 + fr)*64 + kk + kg*8];
      #pragma unroll
      for (int n = 0; n < 4; ++n)
        bfr[n] = *(const bfrag_t*)&Bs[(wc + n*16 + fr)*64 + kk + kg*8];
      #pragma unroll
      for (int m = 0; m < 4; ++m)
        #pragma unroll
        for (int n = 0; n < 4; ++n)
          acc[m][n] = __builtin_amdgcn_mfma_f32_16x16x32_bf16(af[m], bfr[n], acc[m][n], 0, 0, 0);
    }
    __syncthreads();
  }

  const int row0 = bm * 128 + wr + kg * 4;
  const int col0 = bn * 128 + wc + fr;
  if constexpr (EPI == 0) {
    ushort* O = (ushort*)outp;
    #pragma unroll
    for (int n = 0; n < 4; ++n) {
      const float bv = bias[col0 + n*16];
      #pragma unroll
      for (int m = 0; m < 4; ++m)
        #pragma unroll
        for (int rr = 0; rr < 4; ++rr) {
          float v = acc[m][n][rr] + bv;
          v = v > 0.f ? v : 0.f;
          O[(size_t)(row0 + m*16 + rr) * N + (col0 + n*16)] = f2bf(v);
        }
    }
  } else {
    float* O = (float*)outp;
    #pragma unroll
    for (int n = 0; n < 4; ++n) {
      const float bv = bias[col0 + n*16];
      #pragma unroll
      for (int m = 0; m < 4; ++m)
        #pragma unroll
        for (int rr = 0; rr < 4; ++rr) {
          const size_t idx = (size_t)(row0 + m*16 + rr) * N + (col0 + n*16);
          O[idx] = acc[m][n][rr] + bv + addend[idx];
        }
    }
  }
}

extern "C" void kernel_launch(void* const* d_in, const int* in_sizes, int n_in,
                              void* d_out, int out_size, void* d_ws, size_t ws_size,
                              hipStream_t stream) {
  const float* input    = (const float*)d_in[0];
  const float* residual = (const float*)d_in[1];
  // d_in[2] residual_norm: unused by reference
  const float* bias     = (const float*)d_in[3];
  // d_in[4] weight: unused by reference
  const float* ln_w     = (const float*)d_in[5];
  const float* attn_nb  = (const float*)d_in[6];
  const float* inter_w  = (const float*)d_in[7];   // [2048][8192]
  const float* inter_b  = (const float*)d_in[8];
  const float* output_w = (const float*)d_in[9];   // [8192][2048]
  const float* output_b = (const float*)d_in[10];

  char* ws = (char*)d_ws;
  float*  x   = (float*) (ws);                       //  67,108,864 B fp32 [8192][2048]
  ushort* h   = (ushort*)(ws + (size_t)67108864);    //  33,554,432 B bf16 [8192][2048]
  ushort* h1  = (ushort*)(ws + (size_t)100663296);   // 134,217,728 B bf16 [8192][8192]
  ushort* Bt1 = (ushort*)(ws + (size_t)234881024);   //  33,554,432 B bf16 [8192][2048]
  ushort* Bt2 = (ushort*)(ws + (size_t)268435456);   //  33,554,432 B bf16 [2048][8192]
  float* out = (float*)d_out;

  add_ln_kernel<<<8192, 256, 0, stream>>>(input, residual, bias, ln_w, attn_nb, x, h);
  tcast_kernel<<<dim3(128, 32), dim3(64, 4), 0, stream>>>(inter_w,  Bt1, 2048, 8192);
  tcast_kernel<<<dim3(32, 128), dim3(64, 4), 0, stream>>>(output_w, Bt2, 8192, 2048);
  gemm_bt_kernel<0><<<4096, 256, 0, stream>>>(h,  Bt1, inter_b,  nullptr, (void*)h1, 8192, 8192, 2048);
  gemm_bt_kernel<1><<<1024, 256, 0, stream>>>(h1, Bt2, output_b, x,       (void*)out, 8192, 2048, 8192);
}